// Round 7
// baseline (132.092 us; speedup 1.0000x reference)
//
#include <hip/hip_runtime.h>
#include <hip/hip_fp16.h>
#include <math.h>

// ---------------------------------------------------------------------------
// HematoxylinFFTModel round 7: radix-8 register FFT kept; structural fixes:
//  - k_coeff restored as its own 64-block kernel (round-6 fold made 16384
//    norm blocks serially chase 17 dependent partial loads ~ +10 us).
//  - colfft: 256-thr blocks, 4 waves = 4 cols/pass, grid 64x16 = 1024 =
//    exactly 4 blocks/CU x 256 CU -> single resident round, no tail.
//    u=256 column is a 5th pass on g==0 blocks.
//  - XSTR 568 -> 570 (LDS slot spread 10c vs 8c: scatter/stat conflicts
//    drop to ~2-way).
//  - k_norm: 4 row-pairs per block (grid 4096), reads precomputed coeff.
// ---------------------------------------------------------------------------

#define PI_F 3.14159265358979323846f
#define FROW 264            // F row stride in half2 (cols 0..256 live)
#define LMSTR 264           // logmag row stride in u16 (cols 0..256 live)
#define LVMAX 1.6f          // bound: lv = log2(1+mag) <= log2(2.9) < 1.6
#define QE (65535.0f / LVMAX)
#define QD (LVMAX / 65535.0f)
#define XSTR 570            // per-FFT LDS stride in float2 (MU(511)=560)

__device__ __forceinline__ int MU(int p) {
    return ((p >> 6) * 72) + (p & 56) + ((p & 7) ^ ((p >> 3) & 7));
}
// octal digit reversal: k = k2*64 + k1*8 + k0 -> k0*64 + k1*8 + k2
__device__ __forceinline__ int odrev(int k) {
    return ((k & 7) << 6) | (k & 56) | (k >> 6);
}

__device__ __forceinline__ float2 cadd(float2 a, float2 b) { return make_float2(a.x + b.x, a.y + b.y); }
__device__ __forceinline__ float2 csub(float2 a, float2 b) { return make_float2(a.x - b.x, a.y - b.y); }
__device__ __forceinline__ float2 cmul(float2 a, float2 w) {
    return make_float2(a.x * w.x - a.y * w.y, a.x * w.y + a.y * w.x);
}

// 8-point DFT, natural-in / natural-out, w8 = e^{-2pi i/8}
__device__ __forceinline__ void dft8(float2 v[8]) {
    const float s = 0.70710678118654752f;
    float2 a0 = cadd(v[0], v[4]), b0 = csub(v[0], v[4]);
    float2 a1 = cadd(v[1], v[5]), b1 = csub(v[1], v[5]);
    float2 a2 = cadd(v[2], v[6]), b2 = csub(v[2], v[6]);
    float2 a3 = cadd(v[3], v[7]), b3 = csub(v[3], v[7]);
    b1 = make_float2(s * (b1.x + b1.y), s * (b1.y - b1.x));
    b2 = make_float2(b2.y, -b2.x);
    b3 = make_float2(s * (b3.y - b3.x), -s * (b3.x + b3.y));
    float2 c0 = cadd(a0, a2), c1 = cadd(a1, a3);
    float2 d0 = csub(a0, a2), d1 = csub(a1, a3);
    d1 = make_float2(d1.y, -d1.x);
    v[0] = cadd(c0, c1); v[4] = csub(c0, c1);
    v[2] = cadd(d0, d1); v[6] = csub(d0, d1);
    float2 e0 = cadd(b0, b2), e1 = cadd(b1, b3);
    float2 f0 = csub(b0, b2), f1 = csub(b1, b3);
    f1 = make_float2(f1.y, -f1.x);
    v[1] = cadd(e0, e1); v[5] = csub(e0, e1);
    v[3] = cadd(f0, f1); v[7] = csub(f0, f1);
}

// 512-pt wave-synchronous FFT, natural input in Xw[MU(.)], output
// stored[MU(p)] = Z[odrev(p)]. 3 phases, trailing wave_barrier included.
__device__ __forceinline__ void fft512_reg(float2* Xw, const float2* TW, int lane) {
    float2 v[8];
    #pragma unroll
    for (int m = 0; m < 8; ++m) v[m] = Xw[MU(lane + (m << 6))];
    dft8(v);
    #pragma unroll
    for (int m = 1; m < 8; ++m) v[m] = cmul(v[m], TW[(lane * m) & 511]);
    #pragma unroll
    for (int m = 0; m < 8; ++m) Xw[MU((m << 6) + lane)] = v[m];
    __builtin_amdgcn_wave_barrier();
    const int b = lane >> 3, t = lane & 7;
    const int base2 = (b << 6) + t;
    #pragma unroll
    for (int m = 0; m < 8; ++m) v[m] = Xw[MU(base2 + (m << 3))];
    dft8(v);
    #pragma unroll
    for (int m = 1; m < 8; ++m) v[m] = cmul(v[m], TW[(t * m) << 3]);
    #pragma unroll
    for (int m = 0; m < 8; ++m) Xw[MU(base2 + (m << 3))] = v[m];
    __builtin_amdgcn_wave_barrier();
    const int base3 = (b << 6) + (t << 3);
    #pragma unroll
    for (int j = 0; j < 8; ++j) v[j] = Xw[MU(base3 + j)];
    dft8(v);
    #pragma unroll
    for (int sidx = 0; sidx < 8; ++sidx) Xw[MU(base3 + sidx)] = v[sidx];
    __builtin_amdgcn_wave_barrier();
}

__device__ __forceinline__ void hstore(float2* Xw, int c,
                                       float r0v, float g0v, float b0v,
                                       float r1v, float g1v, float b1v,
                                       float w0, float w1, float w2) {
    r0v = fminf(fmaxf(r0v, 1e-6f), 1.0f);
    g0v = fminf(fmaxf(g0v, 1e-6f), 1.0f);
    b0v = fminf(fmaxf(b0v, 1e-6f), 1.0f);
    r1v = fminf(fmaxf(r1v, 1e-6f), 1.0f);
    g1v = fminf(fmaxf(g1v, 1e-6f), 1.0f);
    b1v = fminf(fmaxf(b1v, 1e-6f), 1.0f);
    float h0 = fmaxf(w0 * __log2f(r0v) + w1 * __log2f(g0v) + w2 * __log2f(b0v), 0.0f);
    float h1 = fmaxf(w0 * __log2f(r1v) + w1 * __log2f(g1v) + w2 * __log2f(b1v), 0.0f);
    Xw[MU(c)] = make_float2(h0, h1);
}

// Pass 1: hematoxylin + packed row-pair FFT, 4 waves = 4 FFTs (8 rows)/block.
__global__ __launch_bounds__(256) void k_rowfft(const float* __restrict__ x,
                                                __half2* __restrict__ Fh,
                                                float w0, float w1, float w2) {
    const int b = blockIdx.x >> 6;
    const int p = blockIdx.x & 63;
    __shared__ float2 X[4 * XSTR];
    __shared__ float2 TW[512];
    const int tid = threadIdx.x;
    const int w = tid >> 6, lane = tid & 63;
    #pragma unroll
    for (int t = 0; t < 8; ++t) {
        int idx = lane + (t << 6);
        float sn, cs;
        __sincosf(-PI_F * (float)idx * (1.0f / 256.0f), &sn, &cs);
        TW[idx] = make_float2(cs, sn);      // per-wave redundant, benign
    }
    float2* Xw = X + w * XSTR;
    const float* xb = x + (size_t)b * 786432;
    const int r0 = (p << 3) + (w << 1);

    #pragma unroll
    for (int q = 0; q < 2; ++q) {
        const int cb = (q << 8) + (lane << 2);
        float4 R0 = *(const float4*)(xb +          (r0 << 9) + cb);
        float4 G0 = *(const float4*)(xb + 262144 + (r0 << 9) + cb);
        float4 B0 = *(const float4*)(xb + 524288 + (r0 << 9) + cb);
        float4 R1 = *(const float4*)(xb +          ((r0 + 1) << 9) + cb);
        float4 G1 = *(const float4*)(xb + 262144 + ((r0 + 1) << 9) + cb);
        float4 B1 = *(const float4*)(xb + 524288 + ((r0 + 1) << 9) + cb);
        hstore(Xw, cb + 0, R0.x, G0.x, B0.x, R1.x, G1.x, B1.x, w0, w1, w2);
        hstore(Xw, cb + 1, R0.y, G0.y, B0.y, R1.y, G1.y, B1.y, w0, w1, w2);
        hstore(Xw, cb + 2, R0.z, G0.z, B0.z, R1.z, G1.z, B1.z, w0, w1, w2);
        hstore(Xw, cb + 3, R0.w, G0.w, B0.w, R1.w, G1.w, B1.w, w0, w1, w2);
    }
    __builtin_amdgcn_wave_barrier();

    fft512_reg(Xw, TW, lane);

    __half2* Fb = Fh + (size_t)b * (512 * FROW);
    #pragma unroll
    for (int t = 0; t < 4; ++t) {
        int k = lane + (t << 6);
        int m = (512 - k) & 511;
        float2 zk = Xw[MU(odrev(k))];
        float2 zm = Xw[MU(odrev(m))];
        Fb[r0 * FROW + k]       = __floats2half2_rn(0.5f * (zk.x + zm.x),  0.5f * (zk.y - zm.y));
        Fb[(r0 + 1) * FROW + k] = __floats2half2_rn(0.5f * (zk.y + zm.y), -0.5f * (zk.x - zm.x));
    }
    if (lane == 0) {
        float2 z = Xw[MU(odrev(256))];
        Fb[r0 * FROW + 256]       = __floats2half2_rn(z.x, 0.0f);
        Fb[(r0 + 1) * FROW + 256] = __floats2half2_rn(z.y, 0.0f);
    }
}

// Pass 2: 256 thr / 4 waves; 4 cols per pass (1/wave), 4 passes = 16 cols.
// grid 64 x 16 = 1024 blocks = 4/CU x 256 CU: single resident round.
// g==0 runs a 5th pass for the u=256 column (wave 0 only).
__global__ __launch_bounds__(256, 4) void k_colfft(const __half2* __restrict__ Fh,
                                                   unsigned short* __restrict__ lmu,
                                                   float4* __restrict__ partials) {
    const int b = blockIdx.x >> 4;
    const int g = blockIdx.x & 15;
    __shared__ float2 X[4 * XSTR];
    __shared__ float2 TW[512];
    __shared__ float4 wred[4];
    const int tid = threadIdx.x;
    const int w = tid >> 6, lane = tid & 63;
    {
        float sn, cs;
        __sincosf(-PI_F * (float)tid * (1.0f / 256.0f), &sn, &cs);
        TW[tid] = make_float2(cs, sn);
        TW[tid + 256] = make_float2(-cs, -sn);
    }
    const __half2* Fb = Fh + (size_t)b * (512 * FROW);
    unsigned short* lm_b = lmu + (size_t)b * (512 * LMSTR);
    float mn = 1e30f, mx = -1e30f, s1 = 0.0f, s2 = 0.0f;
    const int npass = (g == 0) ? 5 : 4;

    for (int pass = 0; pass < npass; ++pass) {
        __syncthreads();                    // X free of prev readers; TW ready
        if (pass < 4) {
            const int u0 = (g << 4) + (pass << 2);
            for (int i = tid; i < 2048; i += 256) {
                int y = i >> 2, c = i & 3;
                float2 v = __half22float2(Fb[y * FROW + u0 + c]);
                X[c * XSTR + MU(y)] = v;
            }
        } else {
            for (int i = tid; i < 512; i += 256)
                X[MU(i)] = __half22float2(Fb[i * FROW + 256]);
        }
        __syncthreads();
        if (pass < 4 || w == 0)
            fft512_reg(X + (pass < 4 ? w * XSTR : 0), TW, lane);
        __syncthreads();
        if (pass < 4) {
            const int u0 = (g << 4) + (pass << 2);
            for (int i = tid; i < 2048; i += 256) {
                int k = i >> 2, c = i & 3;
                int u = u0 + c;
                float2 v = X[c * XSTR + MU(odrev(k))];
                float lv = __log2f(1.0f + sqrtf(v.x * v.x + v.y * v.y));
                int ro = (k + 256) & 511;
                unsigned q = (unsigned)__float2uint_rn(fminf(lv, LVMAX) * QE);
                lm_b[ro * LMSTR + u] = (unsigned short)q;
                mn = fminf(mn, lv);
                mx = fmaxf(mx, lv);
                if (u == 0) { s1 += lv;        s2 += lv * lv; }
                else        { s1 += 2.0f * lv; s2 += 2.0f * lv * lv; }
            }
        } else {
            for (int i = tid; i < 512; i += 256) {
                float2 v = X[MU(odrev(i))];
                float lv = __log2f(1.0f + sqrtf(v.x * v.x + v.y * v.y));
                int ro = (i + 256) & 511;
                unsigned q = (unsigned)__float2uint_rn(fminf(lv, LVMAX) * QE);
                lm_b[ro * LMSTR + 256] = (unsigned short)q;
                mn = fminf(mn, lv);
                mx = fmaxf(mx, lv);
                s1 += lv; s2 += lv * lv;    // u=256: not doubled
            }
        }
    }

    #pragma unroll
    for (int off = 32; off > 0; off >>= 1) {
        mn = fminf(mn, __shfl_down(mn, off, 64));
        mx = fmaxf(mx, __shfl_down(mx, off, 64));
        s1 += __shfl_down(s1, off, 64);
        s2 += __shfl_down(s2, off, 64);
    }
    if (lane == 0) wred[w] = make_float4(mn, mx, s1, s2);
    __syncthreads();
    if (tid == 0) {
        float4 r = wred[0];
        #pragma unroll
        for (int wv = 1; wv < 4; ++wv) {
            float4 q2 = wred[wv];
            r.x = fminf(r.x, q2.x);
            r.y = fmaxf(r.y, q2.y);
            r.z += q2.z;
            r.w += q2.w;
        }
        partials[blockIdx.x] = r;
    }
}

// Pass 3: fold 16 partials/image into per-image affine (A,B).
__global__ __launch_bounds__(64) void k_coeff(const float4* __restrict__ partials,
                                              const float* __restrict__ gamma,
                                              const float* __restrict__ beta,
                                              float2* __restrict__ coeff) {
    const int b = blockIdx.x;
    float mn = 1e30f, mx = -1e30f, s1 = 0.0f, s2 = 0.0f;
    if (threadIdx.x < 16) {
        float4 r = partials[(b << 4) + threadIdx.x];
        mn = r.x; mx = r.y; s1 = r.z; s2 = r.w;
    }
    #pragma unroll
    for (int off = 32; off > 0; off >>= 1) {
        mn = fminf(mn, __shfl_down(mn, off, 64));
        mx = fmaxf(mx, __shfl_down(mx, off, 64));
        s1 += __shfl_down(s1, off, 64);
        s2 += __shfl_down(s2, off, 64);
    }
    if (threadIdx.x == 0) {
        const float N = 262144.0f;
        float mean = s1 / N;
        float var = fmaxf(s2 / N - mean * mean, 0.0f);
        float rng = mx - mn;
        float g = gamma[0], bt = beta[0];
        float A, B;
        if (rng > 0.0f) {
            float inv = 1.0f / rng;
            float varn = var * inv * inv;
            float sc = 1.0f / sqrtf(varn + 1e-5f);
            A = g * sc * inv;
            B = bt - mean * A;
        } else {
            A = 0.0f;
            B = bt;
        }
        coeff[b] = make_float2(A, B);
    }
}

// Pass 4: out = A*lv + B with Hermitian mirror reconstruction; 4 row-pairs
// per block (grid 64 x 64).
__global__ __launch_bounds__(256) void k_norm(const unsigned short* __restrict__ lmu,
                                              float* __restrict__ out,
                                              const float2* __restrict__ coeff) {
    const int j = blockIdx.x & 63;
    const int b = blockIdx.x >> 6;
    const float2 ab = coeff[b];
    const float A = ab.x, B = ab.y;
    const unsigned short* lb = lmu + (size_t)b * (512 * LMSTR);
    float* ob = out + ((size_t)b << 18);
    const int tid = threadIdx.x;
    #pragma unroll
    for (int pp = 0; pp < 4; ++pp) {
        const int p = (j << 2) + pp;
        const int rA = p;
        const int rB = (p == 0) ? 256 : 512 - p;
        #pragma unroll
        for (int hh = 0; hh < 2; ++hh) {
            const int r = hh ? rB : rA;
            const int rm = (512 - r) & 511;
            const unsigned short* Ld = lb + (size_t)r * LMSTR;
            const unsigned short* Lm = lb + (size_t)rm * LMSTR;
            float lvd = (float)Ld[tid] * QD;
            ob[(r << 9) + 256 + tid] = A * lvd + B;
            float lvm = (tid == 0) ? ((float)Ld[256] * QD)
                                   : ((float)Lm[256 - tid] * QD);
            ob[(r << 9) + tid] = A * lvm + B;
        }
    }
}

extern "C" void kernel_launch(void* const* d_in, const int* in_sizes, int n_in,
                              void* d_out, int out_size, void* d_ws, size_t ws_size,
                              hipStream_t stream) {
    const float* x     = (const float*)d_in[0];
    const float* gamma = (const float*)d_in[1];
    const float* beta  = (const float*)d_in[2];
    float* out = (float*)d_out;

    // ws: Fh (34.6 MB) | lmu (17.3 MB @40MB) | partials (@60MB) | coeff
    __half2* Fh = (__half2*)d_ws;
    unsigned short* lmu = (unsigned short*)((char*)d_ws + ((size_t)40 << 20));
    float4* partials = (float4*)((char*)d_ws + ((size_t)60 << 20));
    float2* coeff    = (float2*)((char*)d_ws + ((size_t)60 << 20) + 1024 * sizeof(float4));

    const double M00=0.65, M01=0.70, M02=0.29;
    const double M10=0.07, M11=0.99, M12=0.11;
    const double M20=0.27, M21=0.57, M22=0.78;
    const double det = M00*(M11*M22 - M12*M21)
                     - M01*(M10*M22 - M12*M20)
                     + M02*(M10*M21 - M11*M20);
    const float hw0 = (float)( (M11*M22 - M12*M21) / det);
    const float hw1 = (float)(-(M10*M22 - M12*M20) / det);
    const float hw2 = (float)( (M10*M21 - M11*M20) / det);
    const float invLA2 = (float)(log(2.0) / log(1e-6));
    const float sN = 1.0f / (512.0f * 512.0f);
    const float w0 = hw0 * invLA2 * sN;
    const float w1 = hw1 * invLA2 * sN;
    const float w2 = hw2 * invLA2 * sN;

    k_rowfft<<<64 * 64, 256, 0, stream>>>(x, Fh, w0, w1, w2);
    k_colfft<<<64 * 16, 256, 0, stream>>>(Fh, lmu, partials);
    k_coeff<<<64, 64, 0, stream>>>(partials, gamma, beta, coeff);
    k_norm<<<64 * 64, 256, 0, stream>>>(lmu, out, coeff);
}

// Round 8
// 118.323 us; speedup vs baseline: 1.1164x; 1.1164x over previous
//
#include <hip/hip_runtime.h>
#include <hip/hip_fp16.h>
#include <math.h>

// ---------------------------------------------------------------------------
// HematoxylinFFTModel round 8 = round 6 (best, 123us) + two isolated fixes:
//  1. DC/Nyquist column packing: u=0 and u=256 columns of F are REAL ->
//     pack as one complex column; colfft becomes exactly 256 columns =
//     16 groups x 16 cols, grid 64x16=1024 uniform blocks (was 1088 ragged).
//  2. k_coeff back as its own 64-block kernel; k_norm reads coeff[b]
//     (round-6's fold made 16384 blocks serially chase 17 partial loads).
// Round-7's 4-wave colfft + 5th-pass experiment regressed (barriers + wave
// idling + tail imbalance) and is fully reverted.
// ---------------------------------------------------------------------------

#define PI_F 3.14159265358979323846f
#define FROW 264            // F row stride in half2 (cols 0..256 live)
#define LMSTR 264           // logmag row stride in u16 (cols 0..256 live)
#define LVMAX 1.6f          // bound: lv = log2(1+mag) <= log2(2.9) < 1.6
#define QE (65535.0f / LVMAX)
#define QD (LVMAX / 65535.0f)
#define XSTR 568            // per-FFT LDS stride in float2 (MU(511)=560)

__device__ __forceinline__ int MU(int p) {
    return ((p >> 6) * 72) + (p & 56) + ((p & 7) ^ ((p >> 3) & 7));
}
// octal digit reversal: k = k2*64 + k1*8 + k0 -> k0*64 + k1*8 + k2
__device__ __forceinline__ int odrev(int k) {
    return ((k & 7) << 6) | (k & 56) | (k >> 6);
}

__device__ __forceinline__ float2 cadd(float2 a, float2 b) { return make_float2(a.x + b.x, a.y + b.y); }
__device__ __forceinline__ float2 csub(float2 a, float2 b) { return make_float2(a.x - b.x, a.y - b.y); }
__device__ __forceinline__ float2 cmul(float2 a, float2 w) {
    return make_float2(a.x * w.x - a.y * w.y, a.x * w.y + a.y * w.x);
}

// 8-point DFT, natural-in / natural-out, w8 = e^{-2pi i/8}
__device__ __forceinline__ void dft8(float2 v[8]) {
    const float s = 0.70710678118654752f;
    float2 a0 = cadd(v[0], v[4]), b0 = csub(v[0], v[4]);
    float2 a1 = cadd(v[1], v[5]), b1 = csub(v[1], v[5]);
    float2 a2 = cadd(v[2], v[6]), b2 = csub(v[2], v[6]);
    float2 a3 = cadd(v[3], v[7]), b3 = csub(v[3], v[7]);
    b1 = make_float2(s * (b1.x + b1.y), s * (b1.y - b1.x));
    b2 = make_float2(b2.y, -b2.x);
    b3 = make_float2(s * (b3.y - b3.x), -s * (b3.x + b3.y));
    float2 c0 = cadd(a0, a2), c1 = cadd(a1, a3);
    float2 d0 = csub(a0, a2), d1 = csub(a1, a3);
    d1 = make_float2(d1.y, -d1.x);
    v[0] = cadd(c0, c1); v[4] = csub(c0, c1);
    v[2] = cadd(d0, d1); v[6] = csub(d0, d1);
    float2 e0 = cadd(b0, b2), e1 = cadd(b1, b3);
    float2 f0 = csub(b0, b2), f1 = csub(b1, b3);
    f1 = make_float2(f1.y, -f1.x);
    v[1] = cadd(e0, e1); v[5] = csub(e0, e1);
    v[3] = cadd(f0, f1); v[7] = csub(f0, f1);
}

// 512-pt wave-synchronous FFT, natural input in Xw[MU(.)], output
// stored[MU(p)] = Z[odrev(p)]. 3 phases, trailing wave_barrier included.
__device__ __forceinline__ void fft512_reg(float2* Xw, const float2* TW, int lane) {
    float2 v[8];
    #pragma unroll
    for (int m = 0; m < 8; ++m) v[m] = Xw[MU(lane + (m << 6))];
    dft8(v);
    #pragma unroll
    for (int m = 1; m < 8; ++m) v[m] = cmul(v[m], TW[(lane * m) & 511]);
    #pragma unroll
    for (int m = 0; m < 8; ++m) Xw[MU((m << 6) + lane)] = v[m];
    __builtin_amdgcn_wave_barrier();
    const int b = lane >> 3, t = lane & 7;
    const int base2 = (b << 6) + t;
    #pragma unroll
    for (int m = 0; m < 8; ++m) v[m] = Xw[MU(base2 + (m << 3))];
    dft8(v);
    #pragma unroll
    for (int m = 1; m < 8; ++m) v[m] = cmul(v[m], TW[(t * m) << 3]);
    #pragma unroll
    for (int m = 0; m < 8; ++m) Xw[MU(base2 + (m << 3))] = v[m];
    __builtin_amdgcn_wave_barrier();
    const int base3 = (b << 6) + (t << 3);
    #pragma unroll
    for (int j = 0; j < 8; ++j) v[j] = Xw[MU(base3 + j)];
    dft8(v);
    #pragma unroll
    for (int sidx = 0; sidx < 8; ++sidx) Xw[MU(base3 + sidx)] = v[sidx];
    __builtin_amdgcn_wave_barrier();
}

__device__ __forceinline__ void hstore(float2* Xw, int c,
                                       float r0v, float g0v, float b0v,
                                       float r1v, float g1v, float b1v,
                                       float w0, float w1, float w2) {
    r0v = fminf(fmaxf(r0v, 1e-6f), 1.0f);
    g0v = fminf(fmaxf(g0v, 1e-6f), 1.0f);
    b0v = fminf(fmaxf(b0v, 1e-6f), 1.0f);
    r1v = fminf(fmaxf(r1v, 1e-6f), 1.0f);
    g1v = fminf(fmaxf(g1v, 1e-6f), 1.0f);
    b1v = fminf(fmaxf(b1v, 1e-6f), 1.0f);
    float h0 = fmaxf(w0 * __log2f(r0v) + w1 * __log2f(g0v) + w2 * __log2f(b0v), 0.0f);
    float h1 = fmaxf(w0 * __log2f(r1v) + w1 * __log2f(g1v) + w2 * __log2f(b1v), 0.0f);
    Xw[MU(c)] = make_float2(h0, h1);     // natural order (DIF input)
}

// Pass 1: hematoxylin + packed row-pair FFT, 4 waves = 4 FFTs (8 rows)/block.
__global__ __launch_bounds__(256) void k_rowfft(const float* __restrict__ x,
                                                __half2* __restrict__ Fh,
                                                float w0, float w1, float w2) {
    const int b = blockIdx.x >> 6;
    const int p = blockIdx.x & 63;
    __shared__ float2 X[4 * XSTR];
    __shared__ float2 TW[512];
    const int tid = threadIdx.x;
    const int w = tid >> 6, lane = tid & 63;
    #pragma unroll
    for (int t = 0; t < 8; ++t) {
        int idx = lane + (t << 6);
        float sn, cs;
        __sincosf(-PI_F * (float)idx * (1.0f / 256.0f), &sn, &cs);
        TW[idx] = make_float2(cs, sn);      // per-wave redundant, benign
    }
    float2* Xw = X + w * XSTR;
    const float* xb = x + (size_t)b * 786432;
    const int r0 = (p << 3) + (w << 1);

    #pragma unroll
    for (int q = 0; q < 2; ++q) {
        const int cb = (q << 8) + (lane << 2);
        float4 R0 = *(const float4*)(xb +          (r0 << 9) + cb);
        float4 G0 = *(const float4*)(xb + 262144 + (r0 << 9) + cb);
        float4 B0 = *(const float4*)(xb + 524288 + (r0 << 9) + cb);
        float4 R1 = *(const float4*)(xb +          ((r0 + 1) << 9) + cb);
        float4 G1 = *(const float4*)(xb + 262144 + ((r0 + 1) << 9) + cb);
        float4 B1 = *(const float4*)(xb + 524288 + ((r0 + 1) << 9) + cb);
        hstore(Xw, cb + 0, R0.x, G0.x, B0.x, R1.x, G1.x, B1.x, w0, w1, w2);
        hstore(Xw, cb + 1, R0.y, G0.y, B0.y, R1.y, G1.y, B1.y, w0, w1, w2);
        hstore(Xw, cb + 2, R0.z, G0.z, B0.z, R1.z, G1.z, B1.z, w0, w1, w2);
        hstore(Xw, cb + 3, R0.w, G0.w, B0.w, R1.w, G1.w, B1.w, w0, w1, w2);
    }
    __builtin_amdgcn_wave_barrier();

    fft512_reg(Xw, TW, lane);

    __half2* Fb = Fh + (size_t)b * (512 * FROW);
    #pragma unroll
    for (int t = 0; t < 4; ++t) {
        int k = lane + (t << 6);
        int m = (512 - k) & 511;
        float2 zk = Xw[MU(odrev(k))];
        float2 zm = Xw[MU(odrev(m))];
        Fb[r0 * FROW + k]       = __floats2half2_rn(0.5f * (zk.x + zm.x),  0.5f * (zk.y - zm.y));
        Fb[(r0 + 1) * FROW + k] = __floats2half2_rn(0.5f * (zk.y + zm.y), -0.5f * (zk.x - zm.x));
    }
    if (lane == 0) {
        float2 z = Xw[MU(odrev(256))];
        Fb[r0 * FROW + 256]       = __floats2half2_rn(z.x, 0.0f);
        Fb[(r0 + 1) * FROW + 256] = __floats2half2_rn(z.y, 0.0f);
    }
}

// Pass 2: 512 threads, 8 waves; 8 columns per pass (1/wave), 2 passes.
// 16 groups x 16 cols = 256 column-FFTs: u=0 and u=256 (both REAL) are
// packed into one complex column at (g==0, pass==0, c==0).
__global__ __launch_bounds__(512) void k_colfft(const __half2* __restrict__ Fh,
                                                unsigned short* __restrict__ lmu,
                                                float4* __restrict__ partials) {
    const int b = blockIdx.x >> 4;
    const int g = blockIdx.x & 15;
    __shared__ float2 X[8 * XSTR];
    __shared__ float2 TW[512];
    __shared__ float4 wred[8];
    const int tid = threadIdx.x;
    const int w = tid >> 6, lane = tid & 63;
    {
        float sn, cs;
        __sincosf(-PI_F * (float)tid * (1.0f / 256.0f), &sn, &cs);
        TW[tid] = make_float2(cs, sn);
    }
    const __half2* Fb = Fh + (size_t)b * (512 * FROW);
    unsigned short* lm_b = lmu + (size_t)b * (512 * LMSTR);
    float mn = 1e30f, mx = -1e30f, s1 = 0.0f, s2 = 0.0f;

    for (int pass = 0; pass < 2; ++pass) {
        const int u0 = (g << 4) + (pass << 3);
        const bool packpass = (g == 0 && pass == 0);
        __syncthreads();                // prev-pass readers done; TW ready
        for (int i = tid; i < 4096; i += 512) {
            int y = i >> 3, c = i & 7;
            float2 v;
            if (packpass && c == 0) {
                // packed DC/Nyquist column: z = F[y][0].re + i*F[y][256].re
                float2 f0   = __half22float2(Fb[y * FROW]);
                float2 f256 = __half22float2(Fb[y * FROW + 256]);
                v = make_float2(f0.x, f256.x);
            } else {
                v = __half22float2(Fb[y * FROW + u0 + c]);
            }
            X[c * XSTR + MU(y)] = v;    // natural order
        }
        __syncthreads();
        fft512_reg(X + w * XSTR, TW, lane);   // wave w's column
        __syncthreads();
        for (int i = tid; i < 4096; i += 512) {
            int k = i >> 3, c = i & 7;
            int ro = (k + 256) & 511;
            if (packpass && c == 0) {
                // unpack both real columns' spectra
                int m = (512 - k) & 511;
                float2 zk = X[MU(odrev(k))];
                float2 zm = X[MU(odrev(m))];
                float2 c0   = make_float2(0.5f * (zk.x + zm.x),  0.5f * (zk.y - zm.y));
                float2 c256 = make_float2(0.5f * (zk.y + zm.y), -0.5f * (zk.x - zm.x));
                float lv0   = __log2f(1.0f + sqrtf(c0.x * c0.x + c0.y * c0.y));
                float lv256 = __log2f(1.0f + sqrtf(c256.x * c256.x + c256.y * c256.y));
                unsigned q0 = (unsigned)__float2uint_rn(fminf(lv0,   LVMAX) * QE);
                unsigned q6 = (unsigned)__float2uint_rn(fminf(lv256, LVMAX) * QE);
                lm_b[ro * LMSTR]       = (unsigned short)q0;
                lm_b[ro * LMSTR + 256] = (unsigned short)q6;
                mn = fminf(mn, fminf(lv0, lv256));
                mx = fmaxf(mx, fmaxf(lv0, lv256));
                s1 += lv0 + lv256;              // u=0, u=256: counted once
                s2 += lv0 * lv0 + lv256 * lv256;
            } else {
                int u = u0 + c;                 // 1..255: mirrored, 2x weight
                float2 v = X[c * XSTR + MU(odrev(k))];
                float lv = __log2f(1.0f + sqrtf(v.x * v.x + v.y * v.y));
                unsigned q = (unsigned)__float2uint_rn(fminf(lv, LVMAX) * QE);
                lm_b[ro * LMSTR + u] = (unsigned short)q;
                mn = fminf(mn, lv);
                mx = fmaxf(mx, lv);
                s1 += 2.0f * lv;
                s2 += 2.0f * lv * lv;
            }
        }
    }

    #pragma unroll
    for (int off = 32; off > 0; off >>= 1) {
        mn = fminf(mn, __shfl_down(mn, off, 64));
        mx = fmaxf(mx, __shfl_down(mx, off, 64));
        s1 += __shfl_down(s1, off, 64);
        s2 += __shfl_down(s2, off, 64);
    }
    if (lane == 0) wred[w] = make_float4(mn, mx, s1, s2);
    __syncthreads();
    if (tid == 0) {
        float4 r = wred[0];
        #pragma unroll
        for (int wv = 1; wv < 8; ++wv) {
            float4 q2 = wred[wv];
            r.x = fminf(r.x, q2.x);
            r.y = fmaxf(r.y, q2.y);
            r.z += q2.z;
            r.w += q2.w;
        }
        partials[blockIdx.x] = r;
    }
}

// Pass 3: fold 16 partials/image into per-image affine (A,B).
__global__ __launch_bounds__(64) void k_coeff(const float4* __restrict__ partials,
                                              const float* __restrict__ gamma,
                                              const float* __restrict__ beta,
                                              float2* __restrict__ coeff) {
    const int b = blockIdx.x;
    float mn = 1e30f, mx = -1e30f, s1 = 0.0f, s2 = 0.0f;
    if (threadIdx.x < 16) {
        float4 r = partials[(b << 4) + threadIdx.x];
        mn = r.x; mx = r.y; s1 = r.z; s2 = r.w;
    }
    #pragma unroll
    for (int off = 32; off > 0; off >>= 1) {
        mn = fminf(mn, __shfl_down(mn, off, 64));
        mx = fmaxf(mx, __shfl_down(mx, off, 64));
        s1 += __shfl_down(s1, off, 64);
        s2 += __shfl_down(s2, off, 64);
    }
    if (threadIdx.x == 0) {
        const float N = 262144.0f;
        float mean = s1 / N;
        float var = fmaxf(s2 / N - mean * mean, 0.0f);
        float rng = mx - mn;
        float g = gamma[0], bt = beta[0];
        float A, B;
        if (rng > 0.0f) {
            float inv = 1.0f / rng;
            float varn = var * inv * inv;
            float sc = 1.0f / sqrtf(varn + 1e-5f);
            A = g * sc * inv;
            B = bt - mean * A;
        } else {
            A = 0.0f;
            B = bt;
        }
        coeff[b] = make_float2(A, B);
    }
}

// Pass 4: out = A*lv + B, Hermitian mirror reconstruction from half-plane.
__global__ __launch_bounds__(256) void k_norm(const unsigned short* __restrict__ lmu,
                                              float* __restrict__ out,
                                              const float2* __restrict__ coeff) {
    const int p = blockIdx.x & 255;
    const int b = blockIdx.x >> 8;
    const float2 ab = coeff[b];
    const float A = ab.x, B = ab.y;
    const int rA = p;
    const int rB = (p == 0) ? 256 : 512 - p;
    const unsigned short* lb = lmu + (size_t)b * (512 * LMSTR);
    float* ob = out + ((size_t)b << 18);
    const int tid = threadIdx.x;
    #pragma unroll
    for (int hh = 0; hh < 2; ++hh) {
        const int r = hh ? rB : rA;
        const int rm = (512 - r) & 511;
        const unsigned short* Ld = lb + (size_t)r * LMSTR;
        const unsigned short* Lm = lb + (size_t)rm * LMSTR;
        float lvd = (float)Ld[tid] * QD;
        ob[(r << 9) + 256 + tid] = A * lvd + B;
        float lvm = (tid == 0) ? ((float)Ld[256] * QD)
                               : ((float)Lm[256 - tid] * QD);
        ob[(r << 9) + tid] = A * lvm + B;
    }
}

extern "C" void kernel_launch(void* const* d_in, const int* in_sizes, int n_in,
                              void* d_out, int out_size, void* d_ws, size_t ws_size,
                              hipStream_t stream) {
    const float* x     = (const float*)d_in[0];
    const float* gamma = (const float*)d_in[1];
    const float* beta  = (const float*)d_in[2];
    float* out = (float*)d_out;

    // ws: Fh (34.6 MB) | lmu (17.3 MB @40MB) | partials (@60MB) | coeff
    __half2* Fh = (__half2*)d_ws;
    unsigned short* lmu = (unsigned short*)((char*)d_ws + ((size_t)40 << 20));
    float4* partials = (float4*)((char*)d_ws + ((size_t)60 << 20));
    float2* coeff    = (float2*)((char*)d_ws + ((size_t)60 << 20) + 1024 * sizeof(float4));

    const double M00=0.65, M01=0.70, M02=0.29;
    const double M10=0.07, M11=0.99, M12=0.11;
    const double M20=0.27, M21=0.57, M22=0.78;
    const double det = M00*(M11*M22 - M12*M21)
                     - M01*(M10*M22 - M12*M20)
                     + M02*(M10*M21 - M11*M20);
    const float hw0 = (float)( (M11*M22 - M12*M21) / det);
    const float hw1 = (float)(-(M10*M22 - M12*M20) / det);
    const float hw2 = (float)( (M10*M21 - M11*M20) / det);
    const float invLA2 = (float)(log(2.0) / log(1e-6));
    const float sN = 1.0f / (512.0f * 512.0f);
    const float w0 = hw0 * invLA2 * sN;
    const float w1 = hw1 * invLA2 * sN;
    const float w2 = hw2 * invLA2 * sN;

    k_rowfft<<<64 * 64, 256, 0, stream>>>(x, Fh, w0, w1, w2);
    k_colfft<<<64 * 16, 512, 0, stream>>>(Fh, lmu, partials);
    k_coeff<<<64, 64, 0, stream>>>(partials, gamma, beta, coeff);
    k_norm<<<64 * 256, 256, 0, stream>>>(lmu, out, coeff);
}